// Round 2
// baseline (160.640 us; speedup 1.0000x reference)
//
#include <hip/hip_runtime.h>
#include <math.h>

#define BB 8
#define CC 64
#define NN 4096
#define CI 8
#define GAMMA 0.1f

typedef float v2f __attribute__((ext_vector_type(2)));
typedef float v4f __attribute__((ext_vector_type(4)));

__device__ __forceinline__ float fast_exp2(float x) {
    return __builtin_amdgcn_exp2f(x);
}

// Thread per (b, n): compute q,k,v[b][:][n]. Also zeros attab (grid covers it).
// qv layout: [b][n][16] = {q0..q7, v0..v7}  (float4-friendly for LDS staging)
// kb layout: [b][i][N]
__global__ __launch_bounds__(64) void qkv_kernel(
        const float* __restrict__ x,
        const float* __restrict__ Wq, const float* __restrict__ Wk,
        const float* __restrict__ Wv,
        float* __restrict__ qv, float* __restrict__ kb,
        float* __restrict__ attab) {
    __shared__ float sW[3 * CI * CC];   // 6 KB
    int t = threadIdx.x;
    for (int i = t; i < CI * CC; i += blockDim.x) {
        sW[i]               = Wq[i];
        sW[CI * CC + i]     = Wk[i];
        sW[2 * CI * CC + i] = Wv[i];
    }
    int gid = blockIdx.x * blockDim.x + t;   // over BB*NN = 32768
    // zero attab: 9*32768 elements, 9 coalesced passes
    for (int i = gid; i < BB * 9 * NN; i += BB * NN) attab[i] = 0.0f;
    __syncthreads();
    int b = gid >> 12;
    int n = gid & (NN - 1);
    const float* xp = x + ((size_t)b * CC) * NN + n;
    float qa[CI], ka[CI], va[CI];
#pragma unroll
    for (int i = 0; i < CI; ++i) { qa[i] = 0.f; ka[i] = 0.f; va[i] = 0.f; }
#pragma unroll 8
    for (int c = 0; c < CC; ++c) {
        float xv = xp[(size_t)c * NN];
#pragma unroll
        for (int i = 0; i < CI; ++i) {
            qa[i] = fmaf(sW[i * CC + c], xv, qa[i]);
            ka[i] = fmaf(sW[CI * CC + i * CC + c], xv, ka[i]);
            va[i] = fmaf(sW[2 * CI * CC + i * CC + c], xv, va[i]);
        }
    }
    float* qvp = qv + ((size_t)b * NN + n) * 16;
#pragma unroll
    for (int i = 0; i < CI; ++i) { qvp[i] = qa[i]; qvp[8 + i] = va[i]; }
    float* kp = kb + ((size_t)b * CI) * NN + n;
#pragma unroll
    for (int i = 0; i < CI; ++i) kp[(size_t)i * NN] = ka[i];
}

// Attention core. |scores| < ~2 so exp() is safe without max-subtraction
// (softmax is shift-invariant): att[n,m] = e(s_nm)/sum_n e(s_nm).
// Grid: (m-tiles = 4, n-chunks = 32, B). Block = 256 threads, MT=4 columns each.
// attab layout: [b][9][N] -> rows 0..7 = sum_n e*v_i, row 8 = sum_n e.
// Inner loop uses packed fp32 (v_pk_fma_f32 via v2f + elementwise_fma).
#define MT 4
#define NCHUNK 128
__global__ __launch_bounds__(256) void att_kernel(
        const float* __restrict__ qv, const float* __restrict__ kb,
        float* __restrict__ attab) {
    __shared__ float sqv[NCHUNK * 16];   // 8 KB
    const int t = threadIdx.x;
    const int b = blockIdx.z;
    const int n0 = blockIdx.y * NCHUNK;
    const int m0 = blockIdx.x * (256 * MT);

    // stage q/v chunk: 2048 floats = 512 float4
    const float4* src = (const float4*)(qv + ((size_t)b * NN + n0) * 16);
    float4* dst = (float4*)sqv;
    for (int i = t; i < NCHUNK * 4; i += 256) dst[i] = src[i];
    __syncthreads();

    // exp(s/sqrt(8)) = exp2(s * log2(e)/sqrt(8)); fold into k.
    const float scale = 1.44269504088896f * 0.35355339059327f;

    v2f kr[MT][4];
    int mm[MT];
#pragma unroll
    for (int j = 0; j < MT; ++j) {
        int m = m0 + t + 256 * j;
        mm[j] = m;
#pragma unroll
        for (int i = 0; i < 4; ++i) {
            float k0 = kb[((size_t)b * CI + 2 * i) * NN + m] * scale;
            float k1 = kb[((size_t)b * CI + 2 * i + 1) * NN + m] * scale;
            kr[j][i] = (v2f){k0, k1};
        }
    }

    v2f acc[MT][4];
    float es[MT];
#pragma unroll
    for (int j = 0; j < MT; ++j) {
        es[j] = 0.f;
#pragma unroll
        for (int i = 0; i < 4; ++i) acc[j][i] = (v2f){0.f, 0.f};
    }

    for (int n = 0; n < NCHUNK; ++n) {
        const float* p = sqv + n * 16;   // same addr all lanes: LDS broadcast
        v4f qa = *(const v4f*)(p);
        v4f qb = *(const v4f*)(p + 4);
        v4f va = *(const v4f*)(p + 8);
        v4f vb = *(const v4f*)(p + 12);
        v2f q01 = {qa.x, qa.y}, q23 = {qa.z, qa.w};
        v2f q45 = {qb.x, qb.y}, q67 = {qb.z, qb.w};
        v2f v01 = {va.x, va.y}, v23 = {va.z, va.w};
        v2f v45 = {vb.x, vb.y}, v67 = {vb.z, vb.w};
#pragma unroll
        for (int j = 0; j < MT; ++j) {
            v2f s2 = q01 * kr[j][0];
            s2 = __builtin_elementwise_fma(q23, kr[j][1], s2);
            s2 = __builtin_elementwise_fma(q45, kr[j][2], s2);
            s2 = __builtin_elementwise_fma(q67, kr[j][3], s2);
            float e = fast_exp2(s2.x + s2.y);
            es[j] += e;
            v2f e2 = {e, e};
            acc[j][0] = __builtin_elementwise_fma(e2, v01, acc[j][0]);
            acc[j][1] = __builtin_elementwise_fma(e2, v23, acc[j][1]);
            acc[j][2] = __builtin_elementwise_fma(e2, v45, acc[j][2]);
            acc[j][3] = __builtin_elementwise_fma(e2, v67, acc[j][3]);
        }
    }

#pragma unroll
    for (int j = 0; j < MT; ++j) {
        float* ap = attab + (size_t)b * 9 * NN + mm[j];
#pragma unroll
        for (int i = 0; i < 4; ++i) {
            atomicAdd(ap + (size_t)(2 * i) * NN, acc[j][i].x);
            atomicAdd(ap + (size_t)(2 * i + 1) * NN, acc[j][i].y);
        }
        atomicAdd(ap + (size_t)8 * NN, es[j]);
    }
}

// Thread per (b,m): normalize, project with Wout, residual-add.
__global__ __launch_bounds__(64) void out_kernel(
        const float* __restrict__ x, const float* __restrict__ Wout,
        const float* __restrict__ attab, float* __restrict__ out) {
    __shared__ float sW[CC * CI];   // 2 KB
    int t = threadIdx.x;
    for (int i = t; i < CC * CI; i += blockDim.x) sW[i] = Wout[i];
    __syncthreads();
    int gid = blockIdx.x * blockDim.x + t;   // over BB*NN
    int b = gid >> 12;
    int m = gid & (NN - 1);
    const float* ap = attab + (size_t)b * 9 * NN + m;
    float inv = 1.0f / ap[(size_t)8 * NN];
    float ao[CI];
#pragma unroll
    for (int i = 0; i < CI; ++i) ao[i] = ap[(size_t)i * NN] * inv;
    const float* xp = x + ((size_t)b * CC) * NN + m;
    float* op = out + ((size_t)b * CC) * NN + m;
#pragma unroll 8
    for (int c = 0; c < CC; ++c) {
        float s = 0.f;
#pragma unroll
        for (int i = 0; i < CI; ++i) s = fmaf(sW[c * CI + i], ao[i], s);
        op[(size_t)c * NN] = xp[(size_t)c * NN] + GAMMA * s;
    }
}

extern "C" void kernel_launch(void* const* d_in, const int* in_sizes, int n_in,
                              void* d_out, int out_size, void* d_ws, size_t ws_size,
                              hipStream_t stream) {
    const float* x    = (const float*)d_in[0];
    const float* Wq   = (const float*)d_in[1];
    const float* Wk   = (const float*)d_in[2];
    const float* Wv   = (const float*)d_in[3];
    const float* Wout = (const float*)d_in[4];
    float* out = (float*)d_out;
    float* ws  = (float*)d_ws;

    // ws layout (floats): qv [B][N][16] | kb [B][8][N] | attab [B][9][N]
    float* qv    = ws;
    float* kb    = ws + (size_t)BB * NN * 16;
    float* attab = kb + (size_t)BB * CI * NN;

    qkv_kernel<<<(BB * NN) / 64, 64, 0, stream>>>(x, Wq, Wk, Wv, qv, kb, attab);
    att_kernel<<<dim3(NN / (256 * MT), NN / NCHUNK, BB), 256, 0, stream>>>(qv, kb, attab);
    out_kernel<<<(BB * NN) / 64, 64, 0, stream>>>(x, Wout, attab, out);
}

// Round 3
// 140.530 us; speedup vs baseline: 1.1431x; 1.1431x over previous
//
#include <hip/hip_runtime.h>
#include <math.h>

#define BB 8
#define CC 64
#define NN 4096
#define CI 8
#define GAMMA 0.1f
// exp(s/sqrt(8)) = exp2(s * log2(e)/sqrt(8)); folded into k at qkv time.
#define SCALE (1.44269504088896f * 0.35355339059327f)

typedef float v2f __attribute__((ext_vector_type(2)));
typedef float v4f __attribute__((ext_vector_type(4)));

__device__ __forceinline__ float fast_exp2(float x) {
    return __builtin_amdgcn_exp2f(x);
}

// Grid (NN/256, 8, BB); block 256. Thread (b, i, n) computes q_i,k_i,v_i[b][n].
// 4096 waves (4/SIMD) vs the old 512 (0.5/SIMD) — that was the round-2 tail.
// qv layout: [b][n][16] = {q0..q7, v0..v7} (what att's float4 staging wants)
// kb layout: [b][i][N], pre-scaled by SCALE.
// Also zeros attab (grid-stride, before the barrier).
__global__ __launch_bounds__(256) void qkv_kernel(
        const float* __restrict__ x,
        const float* __restrict__ Wq, const float* __restrict__ Wk,
        const float* __restrict__ Wv,
        float* __restrict__ qv, float* __restrict__ kb,
        float* __restrict__ attab) {
    __shared__ float sw[3 * CC];   // rows i of Wq, Wk*SCALE, Wv
    const int t = threadIdx.x;
    const int i = blockIdx.y;
    const int b = blockIdx.z;
    if (t < CC) {
        sw[t]          = Wq[i * CC + t];
        sw[CC + t]     = Wk[i * CC + t] * SCALE;
        sw[2 * CC + t] = Wv[i * CC + t];
    }
    // zero attab: 294912 elements over 262144 threads -> <=2 iters each
    int lin = (((b * 8 + i) * (NN / 256)) + blockIdx.x) * 256 + t;
    for (int idx = lin; idx < BB * 9 * NN; idx += BB * CI * NN) attab[idx] = 0.f;
    __syncthreads();

    const int n = blockIdx.x * 256 + t;
    const float* xp = x + ((size_t)b * CC) * NN + n;
    float qa = 0.f, ka = 0.f, va = 0.f;
#pragma unroll 8
    for (int c = 0; c < CC; ++c) {
        float xv = xp[(size_t)c * NN];       // coalesced over n
        qa = fmaf(sw[c], xv, qa);            // LDS broadcast
        ka = fmaf(sw[CC + c], xv, ka);
        va = fmaf(sw[2 * CC + c], xv, va);
    }
    float* qvp = qv + ((size_t)b * NN + n) * 16;
    qvp[i]     = qa;                         // 4B scatter, stride 64B; L2-resident
    qvp[8 + i] = va;
    kb[((size_t)b * CI + i) * NN + n] = ka;  // coalesced
}

// Attention core (unchanged from the proven 67us version, scale pre-folded).
// |scores| < ~2 so exp without max-subtraction is safe (softmax shift-invariant):
// att[n,m] = e(s_nm)/sum_n e(s_nm).
// Grid: (m-tiles = 4, n-chunks = 32, B). Block = 256 threads, MT=4 columns each.
// attab layout: [b][9][N] -> rows 0..7 = sum_n e*v_i, row 8 = sum_n e.
#define MT 4
#define NCHUNK 128
__global__ __launch_bounds__(256) void att_kernel(
        const float* __restrict__ qv, const float* __restrict__ kb,
        float* __restrict__ attab) {
    __shared__ float sqv[NCHUNK * 16];   // 8 KB
    const int t = threadIdx.x;
    const int b = blockIdx.z;
    const int n0 = blockIdx.y * NCHUNK;
    const int m0 = blockIdx.x * (256 * MT);

    // stage q/v chunk: 2048 floats = 512 float4
    const float4* src = (const float4*)(qv + ((size_t)b * NN + n0) * 16);
    float4* dst = (float4*)sqv;
    for (int i = t; i < NCHUNK * 4; i += 256) dst[i] = src[i];
    __syncthreads();

    v2f kr[MT][4];
    int mm[MT];
#pragma unroll
    for (int j = 0; j < MT; ++j) {
        int m = m0 + t + 256 * j;
        mm[j] = m;
#pragma unroll
        for (int i = 0; i < 4; ++i) {
            float k0 = kb[((size_t)b * CI + 2 * i) * NN + m];
            float k1 = kb[((size_t)b * CI + 2 * i + 1) * NN + m];
            kr[j][i] = (v2f){k0, k1};
        }
    }

    v2f acc[MT][4];
    float es[MT];
#pragma unroll
    for (int j = 0; j < MT; ++j) {
        es[j] = 0.f;
#pragma unroll
        for (int i = 0; i < 4; ++i) acc[j][i] = (v2f){0.f, 0.f};
    }

    for (int n = 0; n < NCHUNK; ++n) {
        const float* p = sqv + n * 16;   // same addr all lanes: LDS broadcast
        v4f qa = *(const v4f*)(p);
        v4f qb = *(const v4f*)(p + 4);
        v4f va = *(const v4f*)(p + 8);
        v4f vb = *(const v4f*)(p + 12);
        v2f q01 = {qa.x, qa.y}, q23 = {qa.z, qa.w};
        v2f q45 = {qb.x, qb.y}, q67 = {qb.z, qb.w};
        v2f v01 = {va.x, va.y}, v23 = {va.z, va.w};
        v2f v45 = {vb.x, vb.y}, v67 = {vb.z, vb.w};
#pragma unroll
        for (int j = 0; j < MT; ++j) {
            v2f s2 = q01 * kr[j][0];
            s2 = __builtin_elementwise_fma(q23, kr[j][1], s2);
            s2 = __builtin_elementwise_fma(q45, kr[j][2], s2);
            s2 = __builtin_elementwise_fma(q67, kr[j][3], s2);
            float e = fast_exp2(s2.x + s2.y);
            es[j] += e;
            v2f e2 = {e, e};
            acc[j][0] = __builtin_elementwise_fma(e2, v01, acc[j][0]);
            acc[j][1] = __builtin_elementwise_fma(e2, v23, acc[j][1]);
            acc[j][2] = __builtin_elementwise_fma(e2, v45, acc[j][2]);
            acc[j][3] = __builtin_elementwise_fma(e2, v67, acc[j][3]);
        }
    }

#pragma unroll
    for (int j = 0; j < MT; ++j) {
        float* ap = attab + (size_t)b * 9 * NN + mm[j];
#pragma unroll
        for (int i = 0; i < 4; ++i) {
            atomicAdd(ap + (size_t)(2 * i) * NN, acc[j][i].x);
            atomicAdd(ap + (size_t)(2 * i + 1) * NN, acc[j][i].y);
        }
        atomicAdd(ap + (size_t)8 * NN, es[j]);
    }
}

// Grid (NN/256, CC, BB); block 256. Thread (b, c, m): one output element.
// 32768 waves; Wout row is block-uniform -> scalar loads; all vmem coalesced.
__global__ __launch_bounds__(256) void out_kernel(
        const float* __restrict__ x, const float* __restrict__ Wout,
        const float* __restrict__ attab, float* __restrict__ out) {
    const int t = threadIdx.x;
    const int c = blockIdx.y;
    const int b = blockIdx.z;
    const int m = blockIdx.x * 256 + t;
    const float* ap = attab + (size_t)b * 9 * NN + m;
    float inv = 1.0f / ap[(size_t)8 * NN];
    float s = 0.f;
#pragma unroll
    for (int i = 0; i < CI; ++i)
        s = fmaf(Wout[c * CI + i], ap[(size_t)i * NN], s);   // Wout: s_load
    size_t o = ((size_t)b * CC + c) * NN + m;
    out[o] = x[o] + GAMMA * (s * inv);
}

extern "C" void kernel_launch(void* const* d_in, const int* in_sizes, int n_in,
                              void* d_out, int out_size, void* d_ws, size_t ws_size,
                              hipStream_t stream) {
    const float* x    = (const float*)d_in[0];
    const float* Wq   = (const float*)d_in[1];
    const float* Wk   = (const float*)d_in[2];
    const float* Wv   = (const float*)d_in[3];
    const float* Wout = (const float*)d_in[4];
    float* out = (float*)d_out;
    float* ws  = (float*)d_ws;

    // ws layout (floats): qv [B][N][16] | kb [B][8][N] | attab [B][9][N]
    float* qv    = ws;
    float* kb    = ws + (size_t)BB * NN * 16;
    float* attab = kb + (size_t)BB * CI * NN;

    qkv_kernel<<<dim3(NN / 256, CI, BB), 256, 0, stream>>>(x, Wq, Wk, Wv, qv, kb, attab);
    att_kernel<<<dim3(NN / (256 * MT), NN / NCHUNK, BB), 256, 0, stream>>>(qv, kb, attab);
    out_kernel<<<dim3(NN / 256, CC, BB), 256, 0, stream>>>(x, Wout, attab, out);
}

// Round 4
// 135.960 us; speedup vs baseline: 1.1815x; 1.0336x over previous
//
#include <hip/hip_runtime.h>
#include <math.h>

#define BB 8
#define CC 64
#define NN 4096
#define CI 8
#define GAMMA 0.1f
// exp(s/sqrt(8)) = exp2(s * log2(e)/sqrt(8)); folded into k at qkv time.
#define SCALE (1.44269504088896f * 0.35355339059327f)

typedef float v2f __attribute__((ext_vector_type(2)));
typedef float v4f __attribute__((ext_vector_type(4)));

__device__ __forceinline__ float fast_exp2(float x) {
    return __builtin_amdgcn_exp2f(x);
}

// Grid (NN/32, BB); block 256 = 8 i-groups x 32 n. Each block: 32-n tile, all i.
// x tile (8 KB) read once per block (i-groups hit L1). Weights via b128 LDS
// broadcasts (same-addr within i-group -> physically free). q/v assembled in a
// padded LDS tile, then written to qv[b][n][16] as COALESCED float4 — replaces
// R3's 4B-stride-64B scatter (64 partial-line RMWs per wave-store, the
// suspected hidden ~60us). kb[b][i][n] coalesced, pre-scaled.
// Also zeros attab before the barrier.
__global__ __launch_bounds__(256) void qkv_kernel(
        const float* __restrict__ x,
        const float* __restrict__ Wq, const float* __restrict__ Wk,
        const float* __restrict__ Wv,
        float* __restrict__ qv, float* __restrict__ kb,
        float* __restrict__ attab) {
    __shared__ float sw[3 * CI * CC];   // 6 KB: Wq | Wk*SCALE | Wv
    __shared__ float sqv[32 * 20];      // 2.5 KB: [n_local][q0..7 v0..7 pad4]
    const int t = threadIdx.x;
    const int i  = t >> 5;          // 0..7
    const int nl = t & 31;          // 0..31
    const int b  = blockIdx.y;
    const int n0 = blockIdx.x * 32;

    for (int idx = t; idx < CI * CC; idx += 256) {
        sw[idx]                = Wq[idx];
        sw[CI * CC + idx]      = Wk[idx] * SCALE;
        sw[2 * CI * CC + idx]  = Wv[idx];
    }
    // zero attab: 294912 elems over 262144 threads (<=2 stores each)
    int lin = (blockIdx.y * (NN / 32) + blockIdx.x) * 256 + t;
    for (int idx = lin; idx < BB * 9 * NN; idx += BB * NN * CI) attab[idx] = 0.f;
    __syncthreads();

    const int n = n0 + nl;
    const float* xp = x + ((size_t)b * CC) * NN + n;
    const v4f* wq4 = (const v4f*)(sw + i * CC);
    const v4f* wk4 = (const v4f*)(sw + CI * CC + i * CC);
    const v4f* wv4 = (const v4f*)(sw + 2 * CI * CC + i * CC);
    float qa = 0.f, ka = 0.f, va = 0.f;
#pragma unroll 4
    for (int c4 = 0; c4 < CC / 4; ++c4) {
        v4f wq = wq4[c4], wk = wk4[c4], wv = wv4[c4];   // LDS broadcast b128
        float x0 = xp[(size_t)(c4 * 4 + 0) * NN];
        float x1 = xp[(size_t)(c4 * 4 + 1) * NN];
        float x2 = xp[(size_t)(c4 * 4 + 2) * NN];
        float x3 = xp[(size_t)(c4 * 4 + 3) * NN];
        qa = fmaf(wq.x, x0, qa); ka = fmaf(wk.x, x0, ka); va = fmaf(wv.x, x0, va);
        qa = fmaf(wq.y, x1, qa); ka = fmaf(wk.y, x1, ka); va = fmaf(wv.y, x1, va);
        qa = fmaf(wq.z, x2, qa); ka = fmaf(wk.z, x2, ka); va = fmaf(wv.z, x2, va);
        qa = fmaf(wq.w, x3, qa); ka = fmaf(wk.w, x3, ka); va = fmaf(wv.w, x3, va);
    }
    kb[((size_t)b * CI + i) * NN + n] = ka;   // coalesced (128B per i-group)
    sqv[nl * 20 + i]     = qa;                // padded: ~4-way conflict, 2 ops
    sqv[nl * 20 + 8 + i] = va;
    __syncthreads();
    // 512 words -> 128 float4, fully coalesced 2KB store
    if (t < 128) {
        int w = t * 4;
        int nn = w >> 4, p = w & 15;
        v4f val = *(const v4f*)(sqv + nn * 20 + p);      // 16B-aligned (80B rows)
        *(v4f*)(qv + ((size_t)b * NN + n0 + nn) * 16 + p) = val;
    }
}

// Attention core. |scores| < ~2 so exp without max-subtraction is safe
// (softmax shift-invariant): att[n,m] = e(s_nm)/sum_n e(s_nm).
// MT=2: grid (8 m-tiles, 32 n-chunks, B) = 2048 blocks = 8192 waves -> 100%
// occupancy cap (was 50% at MT=4; Occupancy measured 27.6%, VALUBusy 63%).
// Atomic count unchanged. attab: [b][9][N], rows 0..7 = sum e*v_i, row 8 = sum e.
#define MT 2
#define NCHUNK 128
__global__ __launch_bounds__(256) void att_kernel(
        const float* __restrict__ qv, const float* __restrict__ kb,
        float* __restrict__ attab) {
    __shared__ float sqv[NCHUNK * 16];   // 8 KB
    const int t = threadIdx.x;
    const int b = blockIdx.z;
    const int n0 = blockIdx.y * NCHUNK;
    const int m0 = blockIdx.x * (256 * MT);

    const float4* src = (const float4*)(qv + ((size_t)b * NN + n0) * 16);
    float4* dst = (float4*)sqv;
    for (int i = t; i < NCHUNK * 4; i += 256) dst[i] = src[i];
    __syncthreads();

    v2f kr[MT][4];
    int mm[MT];
#pragma unroll
    for (int j = 0; j < MT; ++j) {
        int m = m0 + t + 256 * j;
        mm[j] = m;
#pragma unroll
        for (int i = 0; i < 4; ++i) {
            float k0 = kb[((size_t)b * CI + 2 * i) * NN + m];
            float k1 = kb[((size_t)b * CI + 2 * i + 1) * NN + m];
            kr[j][i] = (v2f){k0, k1};
        }
    }

    v2f acc[MT][4];
    float es[MT];
#pragma unroll
    for (int j = 0; j < MT; ++j) {
        es[j] = 0.f;
#pragma unroll
        for (int i = 0; i < 4; ++i) acc[j][i] = (v2f){0.f, 0.f};
    }

    for (int n = 0; n < NCHUNK; ++n) {
        const float* p = sqv + n * 16;   // same addr all lanes: LDS broadcast
        v4f qa = *(const v4f*)(p);
        v4f qb = *(const v4f*)(p + 4);
        v4f va = *(const v4f*)(p + 8);
        v4f vb = *(const v4f*)(p + 12);
        v2f q01 = {qa.x, qa.y}, q23 = {qa.z, qa.w};
        v2f q45 = {qb.x, qb.y}, q67 = {qb.z, qb.w};
        v2f v01 = {va.x, va.y}, v23 = {va.z, va.w};
        v2f v45 = {vb.x, vb.y}, v67 = {vb.z, vb.w};
#pragma unroll
        for (int j = 0; j < MT; ++j) {
            v2f s2 = q01 * kr[j][0];
            s2 = __builtin_elementwise_fma(q23, kr[j][1], s2);
            s2 = __builtin_elementwise_fma(q45, kr[j][2], s2);
            s2 = __builtin_elementwise_fma(q67, kr[j][3], s2);
            float e = fast_exp2(s2.x + s2.y);
            es[j] += e;
            v2f e2 = {e, e};
            acc[j][0] = __builtin_elementwise_fma(e2, v01, acc[j][0]);
            acc[j][1] = __builtin_elementwise_fma(e2, v23, acc[j][1]);
            acc[j][2] = __builtin_elementwise_fma(e2, v45, acc[j][2]);
            acc[j][3] = __builtin_elementwise_fma(e2, v67, acc[j][3]);
        }
    }

#pragma unroll
    for (int j = 0; j < MT; ++j) {
        float* ap = attab + (size_t)b * 9 * NN + mm[j];
#pragma unroll
        for (int i = 0; i < 4; ++i) {
            atomicAdd(ap + (size_t)(2 * i) * NN, acc[j][i].x);
            atomicAdd(ap + (size_t)(2 * i + 1) * NN, acc[j][i].y);
        }
        atomicAdd(ap + (size_t)8 * NN, es[j]);
    }
}

// Grid (NN/256, CC, BB); block 256. Thread (b, c, m): one output element.
// 32768 waves; Wout row block-uniform -> scalar loads; all vmem coalesced.
__global__ __launch_bounds__(256) void out_kernel(
        const float* __restrict__ x, const float* __restrict__ Wout,
        const float* __restrict__ attab, float* __restrict__ out) {
    const int t = threadIdx.x;
    const int c = blockIdx.y;
    const int b = blockIdx.z;
    const int m = blockIdx.x * 256 + t;
    const float* ap = attab + (size_t)b * 9 * NN + m;
    float inv = 1.0f / ap[(size_t)8 * NN];
    float s = 0.f;
#pragma unroll
    for (int i = 0; i < CI; ++i)
        s = fmaf(Wout[c * CI + i], ap[(size_t)i * NN], s);
    size_t o = ((size_t)b * CC + c) * NN + m;
    out[o] = x[o] + GAMMA * (s * inv);
}

extern "C" void kernel_launch(void* const* d_in, const int* in_sizes, int n_in,
                              void* d_out, int out_size, void* d_ws, size_t ws_size,
                              hipStream_t stream) {
    const float* x    = (const float*)d_in[0];
    const float* Wq   = (const float*)d_in[1];
    const float* Wk   = (const float*)d_in[2];
    const float* Wv   = (const float*)d_in[3];
    const float* Wout = (const float*)d_in[4];
    float* out = (float*)d_out;
    float* ws  = (float*)d_ws;

    // ws layout (floats): qv [B][N][16] | kb [B][8][N] | attab [B][9][N]
    float* qv    = ws;
    float* kb    = ws + (size_t)BB * NN * 16;
    float* attab = kb + (size_t)BB * CI * NN;

    qkv_kernel<<<dim3(NN / 32, BB), 256, 0, stream>>>(x, Wq, Wk, Wv, qv, kb, attab);
    att_kernel<<<dim3(NN / (256 * MT), NN / NCHUNK, BB), 256, 0, stream>>>(qv, kb, attab);
    out_kernel<<<dim3(NN / 256, CC, BB), 256, 0, stream>>>(x, Wout, attab, out);
}